// Round 13
// baseline (2972.849 us; speedup 1.0000x reference)
//
#include <hip/hip_runtime.h>
#include <math.h>

#define BN_EPS 1e-5f
#define NSLOT1 15376  // conv1 3600*4 + border 244*4 wave-slots
#define NSLOT2 12544  // conv2 3136*4

typedef __attribute__((ext_vector_type(8))) _Float16 f16x8;
typedef __attribute__((ext_vector_type(4))) float f32x4;

// ---------- helpers ----------

__device__ __forceinline__ float siluf(float v) {
    return v / (1.0f + __expf(-v));
}

// Cubic B-spline basis (4 funcs) on uniform knots g[j] = 2*j - 7.
__device__ __forceinline__ void bspline4(float x, float b[4]) {
    float u = (x + 7.0f) * 0.5f;
    float jf = floorf(u);
    float t = u - jf;
    float t2 = t * t, t3 = t2 * t;
    float omt = 1.0f - t;
    float v0 = t3 * (1.0f / 6.0f);
    float v1 = (-3.0f * t3 + 3.0f * t2 + 3.0f * t + 1.0f) * (1.0f / 6.0f);
    float v2 = (3.0f * t3 - 6.0f * t2 + 4.0f) * (1.0f / 6.0f);
    float v3 = omt * omt * omt * (1.0f / 6.0f);
    int j = (int)jf;
#pragma unroll
    for (int i = 0; i < 4; ++i) {
        int d = j - i;
        b[i] = (d == 0) ? v0 : (d == 1) ? v1 : (d == 2) ? v2 : (d == 3) ? v3 : 0.0f;
    }
}

// ---------- conv1 + fused raw maxpool + stats ----------
// 4 threads per pool-quad (tq bit0 = o-half, bit1 = row-half): acc[2][16].
// CRITICAL: every loop touching acc is FULLY unrolled -- any runtime index
// into acc forces the array to scratch (r12: 5.5 GB traffic, 1585 us).

__global__ __launch_bounds__(256, 4) void conv1_kernel(
        const float* __restrict__ x, const float* __restrict__ bw,
        const float* __restrict__ sw, float* __restrict__ pooled,
        float* __restrict__ part) {
    __shared__ float Wl[12 * 32 * 8];
    __shared__ float Ls[64 * 33];
    for (int j = threadIdx.x; j < 12 * 32 * 5; j += 256) {
        int i = j / 160;
        int r = j - i * 160;
        int o = r / 5;
        int k = r - o * 5;
        Wl[(i * 32 + o) * 8 + k] = (k == 0) ? bw[o * 12 + i]
                                            : sw[(o * 12 + i) * 4 + k - 1];
    }
    __syncthreads();

    int lane = threadIdx.x & 63, wave = threadIdx.x >> 6;
    int tid = blockIdx.x * 256 + threadIdx.x;
    int tq = threadIdx.x & 3;
    int ohalf = tq & 1;
    int prow  = tq >> 1;          // row-half of the 2x2 pool window
    int quad = tid >> 2;          // global pool-quad 0..230399
    int b = quad / 225;
    int cell = quad - b * 225;
    int pm = cell / 15, pn = cell - pm * 15;
    int obase = ohalf * 16;

    float acc[2][16];             // [pool-col][output]
#pragma unroll
    for (int pc = 0; pc < 2; ++pc)
#pragma unroll
        for (int oo = 0; oo < 16; ++oo) acc[pc][oo] = 0.f;

#pragma unroll
    for (int c = 0; c < 3; ++c) {
        // 2x3 input region: rows 2pm+prow .. +1, cols 2pn..2pn+2
        const float* xr = x + (b * 3 + c) * 1024 + (2 * pm + prow) * 32 + 2 * pn;
        float r[2][3];
#pragma unroll
        for (int rr = 0; rr < 2; ++rr) {
            float2 ab = *(const float2*)(xr + rr * 32);
            r[rr][0] = ab.x;
            r[rr][1] = ab.y;
            r[rr][2] = xr[rr * 32 + 2];
        }
#pragma unroll
        for (int dy = 0; dy < 2; ++dy) {
#pragma unroll
            for (int dx = 0; dx < 2; ++dx) {
                int i = c * 4 + dy * 2 + dx;
                float e[2][5];
#pragma unroll
                for (int pc = 0; pc < 2; ++pc) {
                    float v = r[dy][pc + dx];
                    e[pc][0] = siluf(v);
                    bspline4(v, &e[pc][1]);
                }
#pragma unroll
                for (int oo = 0; oo < 16; ++oo) {
                    const float* wp = &Wl[(i * 32 + obase + oo) * 8];
                    float4 w0 = *(const float4*)wp;
                    float w4v = wp[4];
#pragma unroll
                    for (int pc = 0; pc < 2; ++pc) {
                        acc[pc][oo] += e[pc][0] * w0.x + e[pc][1] * w0.y
                                     + e[pc][2] * w0.z + e[pc][3] * w0.w
                                     + e[pc][4] * w4v;
                    }
                }
            }
        }
    }

    // stats: FULLY unrolled (constant indices keep acc in VGPRs).
#pragma unroll
    for (int oo = 0; oo < 16; ++oo) {
        float a0 = acc[0][oo], a1 = acc[1][oo];
        float s  = a0 + a1;
        float s2 = a0 * a0 + a1 * a1;
#pragma unroll
        for (int off = 32; off >= 2; off >>= 1) {
            s  += __shfl_down(s, off, 64);
            s2 += __shfl_down(s2, off, 64);
        }
        if (lane < 2) {
            int o = lane * 16 + oo;
            int slot = blockIdx.x * 4 + wave;
            part[(size_t)(2 * o) * NSLOT1 + slot]     = s;
            part[(size_t)(2 * o + 1) * NSLOT1 + slot] = s2;
        }
    }
    // pooled max: in-thread over 2 cols, cross row-half via shfl_xor(2)
    int quadL = threadIdx.x >> 2;
#pragma unroll
    for (int oo = 0; oo < 16; ++oo) {
        float mx = fmaxf(acc[0][oo], acc[1][oo]);
        mx = fmaxf(mx, __shfl_xor(mx, 2, 64));
        if (prow == 0) Ls[quadL * 33 + obase + oo] = mx;
    }
    __syncthreads();
    // coalesced write: block's contiguous 2048-float range
    float* gout = pooled + (size_t)blockIdx.x * 2048;
#pragma unroll
    for (int j = 0; j < 8; ++j) {
        int idx = threadIdx.x + 256 * j;
        gout[idx] = Ls[idx + (idx >> 5)];
    }
}

// ---------- border patches (py==30 or px==30): stats only ----------

__global__ __launch_bounds__(256, 2) void border_kernel(
        const float* __restrict__ x, const float* __restrict__ bw,
        const float* __restrict__ sw, float* __restrict__ part) {
    __shared__ float Wl[12 * 32 * 8];
    for (int j = threadIdx.x; j < 12 * 32 * 5; j += 256) {
        int i = j / 160;
        int r = j - i * 160;
        int o = r / 5;
        int k = r - o * 5;
        Wl[(i * 32 + o) * 8 + k] = (k == 0) ? bw[o * 12 + i]
                                            : sw[(o * 12 + i) * 4 + k - 1];
    }
    __syncthreads();

    int lane = threadIdx.x & 63, wave = threadIdx.x >> 6;
    int id = blockIdx.x * 256 + threadIdx.x;
    int b = id / 61, j = id - b * 61;
    int py = (j < 31) ? 30 : (j - 31);
    int px = (j < 31) ? j : 30;

    float acc[32];
#pragma unroll
    for (int o = 0; o < 32; ++o) acc[o] = 0.f;
#pragma unroll 1
    for (int i = 0; i < 12; ++i) {
        int c = i >> 2, dy = (i >> 1) & 1, dx = i & 1;
        float v = x[(b * 3 + c) * 1024 + (py + dy) * 32 + px + dx];
        float e[5];
        e[0] = siluf(v);
        bspline4(v, &e[1]);
#pragma unroll
        for (int o = 0; o < 32; ++o) {
            const float* wp = &Wl[(i * 32 + o) * 8];
            float4 w0 = *(const float4*)wp;
            acc[o] += e[0] * w0.x + e[1] * w0.y + e[2] * w0.z
                    + e[3] * w0.w + e[4] * wp[4];
        }
    }
    // FULLY unrolled (constant indices keep acc in VGPRs)
#pragma unroll
    for (int o = 0; o < 32; ++o) {
        float a = acc[o], a2 = acc[o] * acc[o];
#pragma unroll
        for (int off = 32; off > 0; off >>= 1) {
            a  += __shfl_down(a, off, 64);
            a2 += __shfl_down(a2, off, 64);
        }
        if (lane == 0) {
            int slot = 14400 + blockIdx.x * 4 + wave;
            part[(size_t)(2 * o) * NSLOT1 + slot]     = a;
            part[(size_t)(2 * o + 1) * NSLOT1 + slot] = a2;
        }
    }
}

// ---------- pre-convert conv2 weights to f16, k-layout = c*20 + s*5 + f ----------

__global__ __launch_bounds__(256) void wconv16_kernel(
        const float* __restrict__ bw, const float* __restrict__ sw,
        _Float16* __restrict__ Wf) {
    int t = blockIdx.x * 256 + threadIdx.x;
    if (t >= 64 * 640) return;
    int n = t / 640;
    int k = t - n * 640;
    int c = k / 20;
    int r = k - c * 20;
    int s = r / 5;
    int f = r - s * 5;
    float val = (f == 0) ? bw[n * 128 + c * 4 + s]
                         : sw[n * 512 + c * 16 + s * 4 + (f - 1)];
    Wf[t] = (_Float16)val;
}

// ---------- conv2 group-data prefetch ----------

__device__ __forceinline__ void c2_load(
        const float* __restrict__ pooled, const float* __restrict__ stats1,
        const float* __restrict__ g1v, const float* __restrict__ b1v,
        int c, const size_t pwoff[2], float pv[2][4], float pst[4]) {
    pst[0] = stats1[2 * c];
    pst[1] = stats1[2 * c + 1];
    pst[2] = g1v[c];
    pst[3] = b1v[c];
#pragma unroll
    for (int cc = 0; cc < 2; ++cc) {
        const float* pw = pooled + pwoff[cc] + c;
        pv[cc][0] = pw[0];
        pv[cc][1] = pw[32];
        pv[cc][2] = pw[480];
        pv[cc][3] = pw[512];
    }
}

// ---------- conv2 (fp16 MFMA, barrier-free, single-buffer, pipelined) ----------

#define C2_LDW 168

__global__ __launch_bounds__(256, 5) void conv2_kernel(
        const float* __restrict__ pooled, const float* __restrict__ stats1,
        const float* __restrict__ g1v, const float* __restrict__ b1v,
        const _Float16* __restrict__ Wf, float* __restrict__ Pt,
        float* __restrict__ part) {
    __shared__ _Float16 Eh[64 * C2_LDW];

    int t = threadIdx.x;
    int lane = t & 63, wv = t >> 6;
    int quad = lane >> 4, l15 = lane & 15;

    int cl = lane & 7;           // channel within group (8 per group)
    int rl = lane >> 3;          // 0..7; rows rl and rl+8 of this wave's tile
    int m[2];
    size_t pwoff[2];
#pragma unroll
    for (int cc = 0; cc < 2; ++cc) {
        m[cc] = wv * 16 + rl + 8 * cc;
        int patch = blockIdx.x * 64 + m[cc];
        int pb = patch / 196;
        int q = patch - pb * 196;
        int py = q / 14;
        int px = q - py * 14;
        pwoff[cc] = ((size_t)pb * 225 + py * 15 + px) * 32;
    }
    const float invN1 = 1.0f / (1024.0f * 961.0f);

    f32x4 acc[4];
#pragma unroll
    for (int nt = 0; nt < 4; ++nt) acc[nt] = (f32x4){0.f, 0.f, 0.f, 0.f};

    float pv[2][4], pst[4];
    c2_load(pooled, stats1, g1v, b1v, cl, pwoff, pv, pst);

#pragma unroll 1
    for (int g = 0; g < 4; ++g) {
        float mean = pst[0] * invN1;
        float var  = pst[1] * invN1 - mean * mean;
        float sc = rsqrtf(var + BN_EPS) * pst[2];
        float sh = pst[3] - mean * sc;
        float cv[2][4];
#pragma unroll
        for (int cc = 0; cc < 2; ++cc)
#pragma unroll
            for (int s = 0; s < 4; ++s)
                cv[cc][s] = fmaxf(pv[cc][s] * sc + sh, 0.f);
        if (g < 3)
            c2_load(pooled, stats1, g1v, b1v, (g + 1) * 8 + cl, pwoff, pv, pst);
#pragma unroll
        for (int cc = 0; cc < 2; ++cc) {
            float f[20];
#pragma unroll
            for (int s = 0; s < 4; ++s) {
                float v = cv[cc][s];
                f[s * 5] = siluf(v);
                bspline4(v, &f[s * 5 + 1]);
            }
            int* dst = (int*)&Eh[m[cc] * C2_LDW + cl * 20];
#pragma unroll
            for (int i = 0; i < 10; ++i) {
                union { _Float16 h[2]; int i32; } u;
                u.h[0] = (_Float16)f[2 * i];
                u.h[1] = (_Float16)f[2 * i + 1];
                dst[i] = u.i32;
            }
        }
#pragma unroll
        for (int ks = 0; ks < 5; ++ks) {
            int ko = ks * 32 + quad * 8;
            f16x8 a = *(const f16x8*)&Eh[(wv * 16 + l15) * C2_LDW + ko];
#pragma unroll
            for (int nt = 0; nt < 4; ++nt) {
                f16x8 bf = *(const f16x8*)&Wf[(size_t)(nt * 16 + l15) * 640
                                              + g * 160 + ko];
                acc[nt] = __builtin_amdgcn_mfma_f32_16x16x32_f16(a, bf, acc[nt], 0, 0, 0);
            }
        }
    }

    int rowb = blockIdx.x * 64 + wv * 16 + quad * 4;
#pragma unroll
    for (int nt = 0; nt < 4; ++nt) {
        int o = nt * 16 + l15;
#pragma unroll
        for (int reg = 0; reg < 4; ++reg)
            Pt[(size_t)(rowb + reg) * 64 + o] = acc[nt][reg];
    }
    float s[4], s2[4];
#pragma unroll
    for (int nt = 0; nt < 4; ++nt) {
        float a0 = acc[nt][0], a1 = acc[nt][1], a2v = acc[nt][2], a3 = acc[nt][3];
        s[nt]  = a0 + a1 + a2v + a3;
        s2[nt] = a0 * a0 + a1 * a1 + a2v * a2v + a3 * a3;
    }
#pragma unroll
    for (int nt = 0; nt < 4; ++nt) {
        s[nt]  += __shfl_down(s[nt], 16, 64);
        s2[nt] += __shfl_down(s2[nt], 16, 64);
        s[nt]  += __shfl_down(s[nt], 32, 64);
        s2[nt] += __shfl_down(s2[nt], 32, 64);
    }
    if (lane < 16) {
        int slot = blockIdx.x * 4 + wv;
#pragma unroll
        for (int nt = 0; nt < 4; ++nt) {
            int o = nt * 16 + l15;
            part[(size_t)(2 * o) * NSLOT2 + slot]     = s[nt];
            part[(size_t)(2 * o + 1) * NSLOT2 + slot] = s2[nt];
        }
    }
}

// ---------- reduce per-wave partials -> stats ----------

__global__ __launch_bounds__(256) void redstats_kernel(
        const float* __restrict__ part, float* __restrict__ stats, int nblk) {
    int p = blockIdx.x;
    const float* src = part + (size_t)p * nblk;
    float s = 0.f;
    for (int j = threadIdx.x; j < nblk; j += 256) s += src[j];
#pragma unroll
    for (int off = 32; off > 0; off >>= 1) s += __shfl_down(s, off, 64);
    __shared__ float ls[4];
    if ((threadIdx.x & 63) == 0) ls[threadIdx.x >> 6] = s;
    __syncthreads();
    if (threadIdx.x == 0) stats[p] = ls[0] + ls[1] + ls[2] + ls[3];
}

// ---------- stage-2 BN + ReLU + pool from Pt [patch][64] -> pooled2 [b][q2*64+c] ----------

__global__ __launch_bounds__(256) void bnpool2_kernel(
        const float* __restrict__ Pt, const float* __restrict__ stats,
        const float* __restrict__ g, const float* __restrict__ bb,
        float* __restrict__ out) {
    int t = blockIdx.x * 256 + threadIdx.x;
    if (t >= 1024 * 49 * 64) return;
    int c  = t & 63;
    int q2 = (t >> 6) % 49;
    int b  = t / (49 * 64);
    float mean = stats[2 * c] * (1.0f / 200704.0f);
    float var  = stats[2 * c + 1] * (1.0f / 200704.0f) - mean * mean;
    float sc = rsqrtf(var + BN_EPS) * g[c];
    float sh = bb[c] - mean * sc;
    int py2 = q2 / 7, px2 = q2 - py2 * 7;
    int q = (py2 * 2) * 14 + px2 * 2;
    const float* p = Pt + ((size_t)b * 196 + q) * 64 + c;
    float v0 = fmaxf(p[0] * sc + sh, 0.f);
    float v1 = fmaxf(p[64] * sc + sh, 0.f);
    float v2 = fmaxf(p[14 * 64] * sc + sh, 0.f);
    float v3 = fmaxf(p[15 * 64] * sc + sh, 0.f);
    out[t] = fmaxf(fmaxf(v0, v1), fmaxf(v2, v3));
}

// ---------- transpose fc1_w into wT[(q2*64 + c)*64 + o] ----------

__global__ __launch_bounds__(256) void transpose_kernel(
        const float* __restrict__ w, float* __restrict__ wT) {
    int t = blockIdx.x * 256 + threadIdx.x;
    if (t >= 64 * 3136) return;
    int o = t & 63;
    int m = t >> 6;
    int c = m & 63;
    int q2 = m >> 6;
    wT[(size_t)m * 64 + o] = w[(size_t)o * 3136 + c * 49 + q2];
}

// ---------- fc1: pooled2 flat [1024,3136] @ wT -> z [1024,64] ----------

__global__ __launch_bounds__(256) void fc1_kernel(
        const float* __restrict__ xin, const float* __restrict__ wT,
        const float* __restrict__ bias, float* __restrict__ z) {
    __shared__ float xs[4 * 3136];
    __shared__ float red[4][4][64];
    int b0 = blockIdx.x * 4;
    for (int j = threadIdx.x; j < 4 * 3136; j += 256)
        xs[j] = xin[(size_t)b0 * 3136 + j];
    __syncthreads();
    int o = threadIdx.x & 63, q = threadIdx.x >> 6;
    float s0 = 0.f, s1 = 0.f, s2 = 0.f, s3 = 0.f;
    for (int j = q * 784; j < q * 784 + 784; ++j) {
        float wv = wT[(size_t)j * 64 + o];
        s0 += xs[j] * wv;
        s1 += xs[3136 + j] * wv;
        s2 += xs[2 * 3136 + j] * wv;
        s3 += xs[3 * 3136 + j] * wv;
    }
    red[0][q][o] = s0; red[1][q][o] = s1; red[2][q][o] = s2; red[3][q][o] = s3;
    __syncthreads();
    int bb = threadIdx.x >> 6;
    float tot = red[bb][0][o] + red[bb][1][o] + red[bb][2][o] + red[bb][3][o] + bias[o];
    z[((size_t)(b0 + bb)) * 64 + o] = tot;
}

// ---------- bn1d column stats over z [1024,64] ----------

__global__ __launch_bounds__(256) void colstats_kernel(
        const float* __restrict__ z, float* __restrict__ stats) {
    int c = blockIdx.x;
    float s = 0.f, s2 = 0.f;
    for (int b = threadIdx.x; b < 1024; b += 256) {
        float v = z[(size_t)b * 64 + c];
        s += v; s2 += v * v;
    }
#pragma unroll
    for (int off = 32; off > 0; off >>= 1) {
        s  += __shfl_down(s, off, 64);
        s2 += __shfl_down(s2, off, 64);
    }
    __shared__ float ls[8];
    int w = threadIdx.x >> 6;
    if ((threadIdx.x & 63) == 0) { ls[w * 2] = s; ls[w * 2 + 1] = s2; }
    __syncthreads();
    if (threadIdx.x == 0) {
        stats[2 * c]     = ls[0] + ls[2] + ls[4] + ls[6];
        stats[2 * c + 1] = ls[1] + ls[3] + ls[5] + ls[7];
    }
}

// ---------- final: bn1d + relu + fc2 -> out [1024,10] ----------

__global__ __launch_bounds__(256) void final_kernel(
        const float* __restrict__ z, const float* __restrict__ stats,
        const float* __restrict__ g, const float* __restrict__ bb,
        const float* __restrict__ w2, const float* __restrict__ b2,
        float* __restrict__ out) {
    int t = blockIdx.x * 256 + threadIdx.x;
    if (t >= 10240) return;
    int o = t % 10, b = t / 10;
    float acc = b2[o];
#pragma unroll 8
    for (int c = 0; c < 64; ++c) {
        float mean = stats[2 * c] * (1.0f / 1024.0f);
        float var  = stats[2 * c + 1] * (1.0f / 1024.0f) - mean * mean;
        float sc = rsqrtf(var + BN_EPS) * g[c];
        float a = fmaxf(z[(size_t)b * 64 + c] * sc + (bb[c] - mean * sc), 0.f);
        acc += a * w2[o * 64 + c];
    }
    out[t] = acc;
}

// ---------- launch ----------

extern "C" void kernel_launch(void* const* d_in, const int* in_sizes, int n_in,
                              void* d_out, int out_size, void* d_ws, size_t ws_size,
                              hipStream_t stream) {
    const float* x   = (const float*)d_in[0];
    const float* bw1 = (const float*)d_in[1];
    const float* sw1 = (const float*)d_in[2];
    const float* g1  = (const float*)d_in[3];
    const float* b1  = (const float*)d_in[4];
    const float* bw2 = (const float*)d_in[5];
    const float* sw2 = (const float*)d_in[6];
    const float* g2  = (const float*)d_in[7];
    const float* b2v = (const float*)d_in[8];
    const float* fw1 = (const float*)d_in[9];
    const float* fb1 = (const float*)d_in[10];
    const float* g3  = (const float*)d_in[11];
    const float* b3  = (const float*)d_in[12];
    const float* fw2 = (const float*)d_in[13];
    const float* fb2 = (const float*)d_in[14];
    float* out = (float*)d_out;

    char* ws = (char*)d_ws;
    // region A [0, 58 MB): part1 (3.9 MB) during conv1 (dead after redstats1),
    //   then Pt [200704][64] (51.38 MB) + part2 at +51,380,224 (6.4 MB)
    float* part1  = (float*)(ws);
    float* Pt     = (float*)(ws);
    float* part2  = (float*)(ws + 51380224);
    // Wf (80 KB) in the dead gap between region A and region B
    _Float16* Wf  = (_Float16*)(ws + 100000000);
    // region B: pooled raw [1024][225][32] (29.5 MB); later pooled2 [1024,3136]
    float* pooled = (float*)(ws + 125960192);
    float* z      = (float*)(ws + 155451392);   // [1024,64]
    float* wT     = (float*)(ws + 155713536);   // [3136,64]
    float* stats1 = (float*)(ws + 156516352);   // 64 floats
    float* stats2 = (float*)(ws + 156516608);   // 128 floats
    float* stats3 = (float*)(ws + 156517120);   // 128 floats

    transpose_kernel<<<(64 * 3136 + 255) / 256, 256, 0, stream>>>(fw1, wT);
    wconv16_kernel<<<160, 256, 0, stream>>>(bw2, sw2, Wf);

    conv1_kernel<<<3600, 256, 0, stream>>>(x, bw1, sw1, pooled, part1);
    border_kernel<<<244, 256, 0, stream>>>(x, bw1, sw1, part1);
    redstats_kernel<<<64, 256, 0, stream>>>(part1, stats1, NSLOT1);

    conv2_kernel<<<3136, 256, 0, stream>>>(pooled, stats1, g1, b1,
                                           Wf, Pt, part2);
    redstats_kernel<<<128, 256, 0, stream>>>(part2, stats2, NSLOT2);

    float* pooled2 = pooled;  // region B reuse (pooled raw dead after conv2)
    bnpool2_kernel<<<(1024 * 49 * 64 + 255) / 256, 256, 0, stream>>>(
        Pt, stats2, g2, b2v, pooled2);

    fc1_kernel<<<256, 256, 0, stream>>>(pooled2, wT, fb1, z);
    colstats_kernel<<<64, 256, 0, stream>>>(z, stats3);
    final_kernel<<<(10240 + 255) / 256, 256, 0, stream>>>(z, stats3, g3, b3, fw2, fb2, out);
}

// Round 14
// 513.205 us; speedup vs baseline: 5.7927x; 5.7927x over previous
//
#include <hip/hip_runtime.h>
#include <math.h>

#define BN_EPS 1e-5f
#define NSLOT1 8176   // conv1 1800*4 + border 244*4 wave-slots
#define NSLOT2 12544  // conv2 3136*4

typedef __attribute__((ext_vector_type(8))) _Float16 f16x8;
typedef __attribute__((ext_vector_type(4))) float f32x4;

// ---------- helpers ----------

__device__ __forceinline__ float siluf(float v) {
    return v / (1.0f + __expf(-v));
}

// Cubic B-spline basis (4 funcs) on uniform knots g[j] = 2*j - 7.
__device__ __forceinline__ void bspline4(float x, float b[4]) {
    float u = (x + 7.0f) * 0.5f;
    float jf = floorf(u);
    float t = u - jf;
    float t2 = t * t, t3 = t2 * t;
    float omt = 1.0f - t;
    float v0 = t3 * (1.0f / 6.0f);
    float v1 = (-3.0f * t3 + 3.0f * t2 + 3.0f * t + 1.0f) * (1.0f / 6.0f);
    float v2 = (3.0f * t3 - 6.0f * t2 + 4.0f) * (1.0f / 6.0f);
    float v3 = omt * omt * omt * (1.0f / 6.0f);
    int j = (int)jf;
#pragma unroll
    for (int i = 0; i < 4; ++i) {
        int d = j - i;
        b[i] = (d == 0) ? v0 : (d == 1) ? v1 : (d == 2) ? v2 : (d == 3) ? v3 : 0.0f;
    }
}

// ---------- conv1 + fused raw maxpool + stats ----------
// EXACT r9 main loop (measured: SGPR=32, zero scratch): #pragma unroll 1 over
// the 12 windows (full unroll -> scheduler hoists 12 windows' expansions and
// spills acc: r11/r12/r13 = GB-scale scratch). Epilogue: LDS-staged coalesced
// pooled writes (fixes r9's 8x store-scatter amplification).

__global__ __launch_bounds__(256, 4) void conv1_kernel(
        const float* __restrict__ x, const float* __restrict__ bw,
        const float* __restrict__ sw, float* __restrict__ pooled,
        float* __restrict__ part) {
    __shared__ float Wl[12 * 32 * 8];
    __shared__ float Ls[128 * 33];
    for (int j = threadIdx.x; j < 12 * 32 * 5; j += 256) {
        int i = j / 160;
        int r = j - i * 160;
        int o = r / 5;
        int k = r - o * 5;
        Wl[(i * 32 + o) * 8 + k] = (k == 0) ? bw[o * 12 + i]
                                            : sw[(o * 12 + i) * 4 + k - 1];
    }
    __syncthreads();

    int lane = threadIdx.x & 63, wave = threadIdx.x >> 6;
    int tid = blockIdx.x * 256 + threadIdx.x;
    int ohalf = tid & 1;
    int quad = tid >> 1;
    int b = quad / 225;
    int cell = quad - b * 225;
    int pm = cell / 15, pn = cell - pm * 15;
    int obase = ohalf * 16;

    float acc[4][16];
#pragma unroll
    for (int pp = 0; pp < 4; ++pp)
#pragma unroll
        for (int oo = 0; oo < 16; ++oo) acc[pp][oo] = 0.f;

    const float* xb0 = x + (b * 3) * 1024 + (2 * pm) * 32 + 2 * pn;
    float v0, v1, v2, v3;
    v0 = xb0[0]; v1 = xb0[1]; v2 = xb0[32]; v3 = xb0[33];

#pragma unroll 1
    for (int i = 0; i < 12; ++i) {
        // prefetch next window's 4 values
        float n0 = 0.f, n1 = 0.f, n2 = 0.f, n3 = 0.f;
        if (i < 11) {
            int ii = i + 1;
            const float* xb = xb0 + (ii >> 2) * 1024 + (((ii >> 1) & 1) << 5) + (ii & 1);
            n0 = xb[0]; n1 = xb[1]; n2 = xb[32]; n3 = xb[33];
        }
        float e[4][5];
        e[0][0] = siluf(v0); bspline4(v0, &e[0][1]);
        e[1][0] = siluf(v1); bspline4(v1, &e[1][1]);
        e[2][0] = siluf(v2); bspline4(v2, &e[2][1]);
        e[3][0] = siluf(v3); bspline4(v3, &e[3][1]);
#pragma unroll
        for (int oo = 0; oo < 16; ++oo) {
            const float* wp = &Wl[(i * 32 + obase + oo) * 8];
            float4 w0 = *(const float4*)wp;
            float w4v = wp[4];
#pragma unroll
            for (int pp = 0; pp < 4; ++pp) {
                acc[pp][oo] += e[pp][0] * w0.x + e[pp][1] * w0.y + e[pp][2] * w0.z
                             + e[pp][3] * w0.w + e[pp][4] * w4v;
            }
        }
        v0 = n0; v1 = n1; v2 = n2; v3 = n3;
    }

    // pooled max -> padded LDS + stats reduce (r9's loop shape, unroll 1)
    int pairL = threadIdx.x >> 1;
#pragma unroll 1
    for (int oo = 0; oo < 16; ++oo) {
        float a0 = acc[0][oo], a1 = acc[1][oo], a2 = acc[2][oo], a3 = acc[3][oo];
        Ls[pairL * 33 + obase + oo] = fmaxf(fmaxf(a0, a1), fmaxf(a2, a3));
        float s  = a0 + a1 + a2 + a3;
        float s2 = a0 * a0 + a1 * a1 + a2 * a2 + a3 * a3;
#pragma unroll
        for (int off = 32; off >= 2; off >>= 1) {
            s  += __shfl_down(s, off, 64);
            s2 += __shfl_down(s2, off, 64);
        }
        if (lane < 2) {
            int o = lane * 16 + oo;
            int slot = blockIdx.x * 4 + wave;
            part[(size_t)(2 * o) * NSLOT1 + slot]     = s;
            part[(size_t)(2 * o + 1) * NSLOT1 + slot] = s2;
        }
    }
    __syncthreads();
    // coalesced write: block's contiguous 4096-float range
    float* gout = pooled + (size_t)blockIdx.x * 4096;
#pragma unroll
    for (int j = 0; j < 16; ++j) {
        int idx = threadIdx.x + 256 * j;
        gout[idx] = Ls[idx + (idx >> 5)];
    }
}

// ---------- border patches (py==30 or px==30): stats only ----------

__global__ __launch_bounds__(256, 2) void border_kernel(
        const float* __restrict__ x, const float* __restrict__ bw,
        const float* __restrict__ sw, float* __restrict__ part) {
    __shared__ float Wl[12 * 32 * 8];
    for (int j = threadIdx.x; j < 12 * 32 * 5; j += 256) {
        int i = j / 160;
        int r = j - i * 160;
        int o = r / 5;
        int k = r - o * 5;
        Wl[(i * 32 + o) * 8 + k] = (k == 0) ? bw[o * 12 + i]
                                            : sw[(o * 12 + i) * 4 + k - 1];
    }
    __syncthreads();

    int lane = threadIdx.x & 63, wave = threadIdx.x >> 6;
    int id = blockIdx.x * 256 + threadIdx.x;
    int b = id / 61, j = id - b * 61;
    int py = (j < 31) ? 30 : (j - 31);
    int px = (j < 31) ? j : 30;

    float acc[32];
#pragma unroll
    for (int o = 0; o < 32; ++o) acc[o] = 0.f;
#pragma unroll 1
    for (int i = 0; i < 12; ++i) {
        int c = i >> 2, dy = (i >> 1) & 1, dx = i & 1;
        float v = x[(b * 3 + c) * 1024 + (py + dy) * 32 + px + dx];
        float e[5];
        e[0] = siluf(v);
        bspline4(v, &e[1]);
#pragma unroll
        for (int o = 0; o < 32; ++o) {
            const float* wp = &Wl[(i * 32 + o) * 8];
            float4 w0 = *(const float4*)wp;
            acc[o] += e[0] * w0.x + e[1] * w0.y + e[2] * w0.z
                    + e[3] * w0.w + e[4] * wp[4];
        }
    }
#pragma unroll 1
    for (int o = 0; o < 32; ++o) {
        float a = acc[o], a2 = acc[o] * acc[o];
#pragma unroll
        for (int off = 32; off > 0; off >>= 1) {
            a  += __shfl_down(a, off, 64);
            a2 += __shfl_down(a2, off, 64);
        }
        if (lane == 0) {
            int slot = 7200 + blockIdx.x * 4 + wave;
            part[(size_t)(2 * o) * NSLOT1 + slot]     = a;
            part[(size_t)(2 * o + 1) * NSLOT1 + slot] = a2;
        }
    }
}

// ---------- pre-convert conv2 weights to f16, k-layout = c*20 + s*5 + f ----------

__global__ __launch_bounds__(256) void wconv16_kernel(
        const float* __restrict__ bw, const float* __restrict__ sw,
        _Float16* __restrict__ Wf) {
    int t = blockIdx.x * 256 + threadIdx.x;
    if (t >= 64 * 640) return;
    int n = t / 640;
    int k = t - n * 640;
    int c = k / 20;
    int r = k - c * 20;
    int s = r / 5;
    int f = r - s * 5;
    float val = (f == 0) ? bw[n * 128 + c * 4 + s]
                         : sw[n * 512 + c * 16 + s * 4 + (f - 1)];
    Wf[t] = (_Float16)val;
}

// ---------- conv2 group-data prefetch ----------

__device__ __forceinline__ void c2_load(
        const float* __restrict__ pooled, const float* __restrict__ stats1,
        const float* __restrict__ g1v, const float* __restrict__ b1v,
        int c, const size_t pwoff[2], float pv[2][4], float pst[4]) {
    pst[0] = stats1[2 * c];
    pst[1] = stats1[2 * c + 1];
    pst[2] = g1v[c];
    pst[3] = b1v[c];
#pragma unroll
    for (int cc = 0; cc < 2; ++cc) {
        const float* pw = pooled + pwoff[cc] + c;
        pv[cc][0] = pw[0];
        pv[cc][1] = pw[32];
        pv[cc][2] = pw[480];
        pv[cc][3] = pw[512];
    }
}

// ---------- conv2 (fp16 MFMA, barrier-free, single-buffer, pipelined) ----------

#define C2_LDW 168

__global__ __launch_bounds__(256, 5) void conv2_kernel(
        const float* __restrict__ pooled, const float* __restrict__ stats1,
        const float* __restrict__ g1v, const float* __restrict__ b1v,
        const _Float16* __restrict__ Wf, float* __restrict__ Pt,
        float* __restrict__ part) {
    __shared__ _Float16 Eh[64 * C2_LDW];

    int t = threadIdx.x;
    int lane = t & 63, wv = t >> 6;
    int quad = lane >> 4, l15 = lane & 15;

    int cl = lane & 7;           // channel within group (8 per group)
    int rl = lane >> 3;          // 0..7; rows rl and rl+8 of this wave's tile
    int m[2];
    size_t pwoff[2];
#pragma unroll
    for (int cc = 0; cc < 2; ++cc) {
        m[cc] = wv * 16 + rl + 8 * cc;
        int patch = blockIdx.x * 64 + m[cc];
        int pb = patch / 196;
        int q = patch - pb * 196;
        int py = q / 14;
        int px = q - py * 14;
        pwoff[cc] = ((size_t)pb * 225 + py * 15 + px) * 32;
    }
    const float invN1 = 1.0f / (1024.0f * 961.0f);

    f32x4 acc[4];
#pragma unroll
    for (int nt = 0; nt < 4; ++nt) acc[nt] = (f32x4){0.f, 0.f, 0.f, 0.f};

    float pv[2][4], pst[4];
    c2_load(pooled, stats1, g1v, b1v, cl, pwoff, pv, pst);

#pragma unroll 1
    for (int g = 0; g < 4; ++g) {
        float mean = pst[0] * invN1;
        float var  = pst[1] * invN1 - mean * mean;
        float sc = rsqrtf(var + BN_EPS) * pst[2];
        float sh = pst[3] - mean * sc;
        float cv[2][4];
#pragma unroll
        for (int cc = 0; cc < 2; ++cc)
#pragma unroll
            for (int s = 0; s < 4; ++s)
                cv[cc][s] = fmaxf(pv[cc][s] * sc + sh, 0.f);
        if (g < 3)
            c2_load(pooled, stats1, g1v, b1v, (g + 1) * 8 + cl, pwoff, pv, pst);
#pragma unroll
        for (int cc = 0; cc < 2; ++cc) {
            float f[20];
#pragma unroll
            for (int s = 0; s < 4; ++s) {
                float v = cv[cc][s];
                f[s * 5] = siluf(v);
                bspline4(v, &f[s * 5 + 1]);
            }
            int* dst = (int*)&Eh[m[cc] * C2_LDW + cl * 20];
#pragma unroll
            for (int i = 0; i < 10; ++i) {
                union { _Float16 h[2]; int i32; } u;
                u.h[0] = (_Float16)f[2 * i];
                u.h[1] = (_Float16)f[2 * i + 1];
                dst[i] = u.i32;
            }
        }
#pragma unroll
        for (int ks = 0; ks < 5; ++ks) {
            int ko = ks * 32 + quad * 8;
            f16x8 a = *(const f16x8*)&Eh[(wv * 16 + l15) * C2_LDW + ko];
#pragma unroll
            for (int nt = 0; nt < 4; ++nt) {
                f16x8 bf = *(const f16x8*)&Wf[(size_t)(nt * 16 + l15) * 640
                                              + g * 160 + ko];
                acc[nt] = __builtin_amdgcn_mfma_f32_16x16x32_f16(a, bf, acc[nt], 0, 0, 0);
            }
        }
    }

    int rowb = blockIdx.x * 64 + wv * 16 + quad * 4;
#pragma unroll
    for (int nt = 0; nt < 4; ++nt) {
        int o = nt * 16 + l15;
#pragma unroll
        for (int reg = 0; reg < 4; ++reg)
            Pt[(size_t)(rowb + reg) * 64 + o] = acc[nt][reg];
    }
    float s[4], s2[4];
#pragma unroll
    for (int nt = 0; nt < 4; ++nt) {
        float a0 = acc[nt][0], a1 = acc[nt][1], a2v = acc[nt][2], a3 = acc[nt][3];
        s[nt]  = a0 + a1 + a2v + a3;
        s2[nt] = a0 * a0 + a1 * a1 + a2v * a2v + a3 * a3;
    }
#pragma unroll
    for (int nt = 0; nt < 4; ++nt) {
        s[nt]  += __shfl_down(s[nt], 16, 64);
        s2[nt] += __shfl_down(s2[nt], 16, 64);
        s[nt]  += __shfl_down(s[nt], 32, 64);
        s2[nt] += __shfl_down(s2[nt], 32, 64);
    }
    if (lane < 16) {
        int slot = blockIdx.x * 4 + wv;
#pragma unroll
        for (int nt = 0; nt < 4; ++nt) {
            int o = nt * 16 + l15;
            part[(size_t)(2 * o) * NSLOT2 + slot]     = s[nt];
            part[(size_t)(2 * o + 1) * NSLOT2 + slot] = s2[nt];
        }
    }
}

// ---------- reduce per-wave partials -> stats ----------

__global__ __launch_bounds__(256) void redstats_kernel(
        const float* __restrict__ part, float* __restrict__ stats, int nblk) {
    int p = blockIdx.x;
    const float* src = part + (size_t)p * nblk;
    float s = 0.f;
    for (int j = threadIdx.x; j < nblk; j += 256) s += src[j];
#pragma unroll
    for (int off = 32; off > 0; off >>= 1) s += __shfl_down(s, off, 64);
    __shared__ float ls[4];
    if ((threadIdx.x & 63) == 0) ls[threadIdx.x >> 6] = s;
    __syncthreads();
    if (threadIdx.x == 0) stats[p] = ls[0] + ls[1] + ls[2] + ls[3];
}

// ---------- stage-2 BN + ReLU + pool from Pt [patch][64] -> pooled2 [b][q2*64+c] ----------

__global__ __launch_bounds__(256) void bnpool2_kernel(
        const float* __restrict__ Pt, const float* __restrict__ stats,
        const float* __restrict__ g, const float* __restrict__ bb,
        float* __restrict__ out) {
    int t = blockIdx.x * 256 + threadIdx.x;
    if (t >= 1024 * 49 * 64) return;
    int c  = t & 63;
    int q2 = (t >> 6) % 49;
    int b  = t / (49 * 64);
    float mean = stats[2 * c] * (1.0f / 200704.0f);
    float var  = stats[2 * c + 1] * (1.0f / 200704.0f) - mean * mean;
    float sc = rsqrtf(var + BN_EPS) * g[c];
    float sh = bb[c] - mean * sc;
    int py2 = q2 / 7, px2 = q2 - py2 * 7;
    int q = (py2 * 2) * 14 + px2 * 2;
    const float* p = Pt + ((size_t)b * 196 + q) * 64 + c;
    float v0 = fmaxf(p[0] * sc + sh, 0.f);
    float v1 = fmaxf(p[64] * sc + sh, 0.f);
    float v2 = fmaxf(p[14 * 64] * sc + sh, 0.f);
    float v3 = fmaxf(p[15 * 64] * sc + sh, 0.f);
    out[t] = fmaxf(fmaxf(v0, v1), fmaxf(v2, v3));
}

// ---------- transpose fc1_w into wT[(q2*64 + c)*64 + o] ----------

__global__ __launch_bounds__(256) void transpose_kernel(
        const float* __restrict__ w, float* __restrict__ wT) {
    int t = blockIdx.x * 256 + threadIdx.x;
    if (t >= 64 * 3136) return;
    int o = t & 63;
    int m = t >> 6;
    int c = m & 63;
    int q2 = m >> 6;
    wT[(size_t)m * 64 + o] = w[(size_t)o * 3136 + c * 49 + q2];
}

// ---------- fc1: pooled2 flat [1024,3136] @ wT -> z [1024,64] ----------

__global__ __launch_bounds__(256) void fc1_kernel(
        const float* __restrict__ xin, const float* __restrict__ wT,
        const float* __restrict__ bias, float* __restrict__ z) {
    __shared__ float xs[4 * 3136];
    __shared__ float red[4][4][64];
    int b0 = blockIdx.x * 4;
    for (int j = threadIdx.x; j < 4 * 3136; j += 256)
        xs[j] = xin[(size_t)b0 * 3136 + j];
    __syncthreads();
    int o = threadIdx.x & 63, q = threadIdx.x >> 6;
    float s0 = 0.f, s1 = 0.f, s2 = 0.f, s3 = 0.f;
    for (int j = q * 784; j < q * 784 + 784; ++j) {
        float wv = wT[(size_t)j * 64 + o];
        s0 += xs[j] * wv;
        s1 += xs[3136 + j] * wv;
        s2 += xs[2 * 3136 + j] * wv;
        s3 += xs[3 * 3136 + j] * wv;
    }
    red[0][q][o] = s0; red[1][q][o] = s1; red[2][q][o] = s2; red[3][q][o] = s3;
    __syncthreads();
    int bb = threadIdx.x >> 6;
    float tot = red[bb][0][o] + red[bb][1][o] + red[bb][2][o] + red[bb][3][o] + bias[o];
    z[((size_t)(b0 + bb)) * 64 + o] = tot;
}

// ---------- bn1d column stats over z [1024,64] ----------

__global__ __launch_bounds__(256) void colstats_kernel(
        const float* __restrict__ z, float* __restrict__ stats) {
    int c = blockIdx.x;
    float s = 0.f, s2 = 0.f;
    for (int b = threadIdx.x; b < 1024; b += 256) {
        float v = z[(size_t)b * 64 + c];
        s += v; s2 += v * v;
    }
#pragma unroll
    for (int off = 32; off > 0; off >>= 1) {
        s  += __shfl_down(s, off, 64);
        s2 += __shfl_down(s2, off, 64);
    }
    __shared__ float ls[8];
    int w = threadIdx.x >> 6;
    if ((threadIdx.x & 63) == 0) { ls[w * 2] = s; ls[w * 2 + 1] = s2; }
    __syncthreads();
    if (threadIdx.x == 0) {
        stats[2 * c]     = ls[0] + ls[2] + ls[4] + ls[6];
        stats[2 * c + 1] = ls[1] + ls[3] + ls[5] + ls[7];
    }
}

// ---------- final: bn1d + relu + fc2 -> out [1024,10] ----------

__global__ __launch_bounds__(256) void final_kernel(
        const float* __restrict__ z, const float* __restrict__ stats,
        const float* __restrict__ g, const float* __restrict__ bb,
        const float* __restrict__ w2, const float* __restrict__ b2,
        float* __restrict__ out) {
    int t = blockIdx.x * 256 + threadIdx.x;
    if (t >= 10240) return;
    int o = t % 10, b = t / 10;
    float acc = b2[o];
#pragma unroll 8
    for (int c = 0; c < 64; ++c) {
        float mean = stats[2 * c] * (1.0f / 1024.0f);
        float var  = stats[2 * c + 1] * (1.0f / 1024.0f) - mean * mean;
        float sc = rsqrtf(var + BN_EPS) * g[c];
        float a = fmaxf(z[(size_t)b * 64 + c] * sc + (bb[c] - mean * sc), 0.f);
        acc += a * w2[o * 64 + c];
    }
    out[t] = acc;
}

// ---------- launch ----------

extern "C" void kernel_launch(void* const* d_in, const int* in_sizes, int n_in,
                              void* d_out, int out_size, void* d_ws, size_t ws_size,
                              hipStream_t stream) {
    const float* x   = (const float*)d_in[0];
    const float* bw1 = (const float*)d_in[1];
    const float* sw1 = (const float*)d_in[2];
    const float* g1  = (const float*)d_in[3];
    const float* b1  = (const float*)d_in[4];
    const float* bw2 = (const float*)d_in[5];
    const float* sw2 = (const float*)d_in[6];
    const float* g2  = (const float*)d_in[7];
    const float* b2v = (const float*)d_in[8];
    const float* fw1 = (const float*)d_in[9];
    const float* fb1 = (const float*)d_in[10];
    const float* g3  = (const float*)d_in[11];
    const float* b3  = (const float*)d_in[12];
    const float* fw2 = (const float*)d_in[13];
    const float* fb2 = (const float*)d_in[14];
    float* out = (float*)d_out;

    char* ws = (char*)d_ws;
    // region A [0, 58 MB): part1 (2.1 MB) during conv1 (dead after redstats1),
    //   then Pt [200704][64] (51.38 MB) + part2 at +51,380,224 (6.4 MB)
    float* part1  = (float*)(ws);
    float* Pt     = (float*)(ws);
    float* part2  = (float*)(ws + 51380224);
    // Wf (80 KB) in the dead gap between region A and region B
    _Float16* Wf  = (_Float16*)(ws + 100000000);
    // region B: pooled raw [1024][225][32] (29.5 MB); later pooled2 [1024,3136]
    float* pooled = (float*)(ws + 125960192);
    float* z      = (float*)(ws + 155451392);   // [1024,64]
    float* wT     = (float*)(ws + 155713536);   // [3136,64]
    float* stats1 = (float*)(ws + 156516352);   // 64 floats
    float* stats2 = (float*)(ws + 156516608);   // 128 floats
    float* stats3 = (float*)(ws + 156517120);   // 128 floats

    transpose_kernel<<<(64 * 3136 + 255) / 256, 256, 0, stream>>>(fw1, wT);
    wconv16_kernel<<<160, 256, 0, stream>>>(bw2, sw2, Wf);

    conv1_kernel<<<1800, 256, 0, stream>>>(x, bw1, sw1, pooled, part1);
    border_kernel<<<244, 256, 0, stream>>>(x, bw1, sw1, part1);
    redstats_kernel<<<64, 256, 0, stream>>>(part1, stats1, NSLOT1);

    conv2_kernel<<<3136, 256, 0, stream>>>(pooled, stats1, g1, b1,
                                           Wf, Pt, part2);
    redstats_kernel<<<128, 256, 0, stream>>>(part2, stats2, NSLOT2);

    float* pooled2 = pooled;  // region B reuse (pooled raw dead after conv2)
    bnpool2_kernel<<<(1024 * 49 * 64 + 255) / 256, 256, 0, stream>>>(
        Pt, stats2, g2, b2v, pooled2);

    fc1_kernel<<<256, 256, 0, stream>>>(pooled2, wT, fb1, z);
    colstats_kernel<<<64, 256, 0, stream>>>(z, stats3);
    final_kernel<<<(10240 + 255) / 256, 256, 0, stream>>>(z, stats3, g3, b3, fw2, fb2, out);
}